// Round 9
// baseline (99.064 us; speedup 1.0000x reference)
//
#include <hip/hip_runtime.h>
#include <stdint.h>

typedef __bf16 bf16;
typedef __bf16 bf16x8 __attribute__((ext_vector_type(8)));
typedef float f32x4 __attribute__((ext_vector_type(4)));

#define LQn   2048
#define LKVn  1024
#define DM    512

static __device__ __forceinline__ f32x4 mfma_bf16(bf16x8 a, bf16x8 b, f32x4 c) {
  return __builtin_amdgcn_mfma_f32_16x16x32_bf16(a, b, c, 0, 0, 0);
}

// ---- global barrier: 256 slots (one per block), zeroed by hipMemsetAsync
// before each launch. Arrive: slot[bid]+=1. Pass: all slots >= 1.
// threadfence release/acquire handles cross-XCD L2 non-coherence.
static __device__ __forceinline__ void gbar(unsigned* slots) {
  __syncthreads();
  if (threadIdx.x == 0) {
    __threadfence();                       // release: WB own-XCD L2
    atomicAdd(&slots[blockIdx.x], 1u);
  }
  if (threadIdx.x < 256) {
    while (__hip_atomic_load(&slots[threadIdx.x], __ATOMIC_RELAXED,
                             __HIP_MEMORY_SCOPE_AGENT) < 1u)
      __builtin_amdgcn_s_sleep(8);
  }
  __syncthreads();
  if (threadIdx.x == 0) __threadfence();   // acquire: INV stale caches
  __syncthreads();
}

// ---- proj job: A-stationary. Stage 32-row A-slab (fp32 -> bf16 hi/lo) in
// LDS once; k-loop is BARRIER-FREE; B-frags streamed from L2-hot WT with
// 1-deep register prefetch. Wave w owns n in [w*64, w*64+64).
// Per-output FMA sequence identical to prior rounds (k ascending, hi then lo).
template <bool SPLIT>
static __device__ __forceinline__ void proj_job(const float* __restrict__ Ap,
                                                const bf16* __restrict__ WTm,
                                                bf16* __restrict__ Ch,
                                                bf16* __restrict__ Cl,
                                                int m0, bf16* smAh, bf16* smAl) {
  const int t = threadIdx.x;
  const int lane = t & 63, w = t >> 6;
  const int ln = lane & 15, hi4 = lane >> 4;

  // stage A-slab [32][512], unit-swizzled (phys = u ^ (r&7) on low 3 bits)
#pragma unroll
  for (int i = 0; i < 4; ++i) {
    int r = i * 8 + w;              // wave-uniform row
    int u = lane;                   // 64 units of 8 floats = full row
    const float* g = Ap + (size_t)(m0 + r) * 512 + u * 8;
    f32x4 x0 = *(const f32x4*)g, x1 = *(const f32x4*)(g + 4);
    bf16x8 hv, lv;
#pragma unroll
    for (int e = 0; e < 4; ++e) {
      float x = x0[e]; bf16 hh = (bf16)x; hv[e] = hh;
      float y = x1[e]; bf16 h2 = (bf16)y; hv[4 + e] = h2;
      if constexpr (SPLIT) { lv[e] = (bf16)(x - (float)hh); lv[4 + e] = (bf16)(y - (float)h2); }
    }
    int phys = (u & ~7) | ((u & 7) ^ (r & 7));
    *(bf16x8*)&smAh[r * 512 + phys * 8] = hv;
    if constexpr (SPLIT) *(bf16x8*)&smAl[r * 512 + phys * 8] = lv;
  }
  __syncthreads();

  const bf16* gB = WTm + (size_t)(w * 64 + ln) * 512 + hi4 * 8;
  const f32x4 zf = {0.f, 0.f, 0.f, 0.f};
  f32x4 acc[2][4];
#pragma unroll
  for (int a = 0; a < 2; ++a)
#pragma unroll
    for (int b = 0; b < 4; ++b) acc[a][b] = zf;

  bf16x8 bc[4], bn[4];
#pragma unroll
  for (int nf = 0; nf < 4; ++nf)
    bc[nf] = *(const bf16x8*)(gB + (size_t)nf * 16 * 512);
#pragma unroll
  for (int it = 0; it < 16; ++it) {        // k = it*32 + hi4*8, ascending
    if (it < 15) {
#pragma unroll
      for (int nf = 0; nf < 4; ++nf)
        bn[nf] = *(const bf16x8*)(gB + (size_t)nf * 16 * 512 + (it + 1) * 32);
    }
    bf16x8 ah[2], al[2];
#pragma unroll
    for (int mf = 0; mf < 2; ++mf) {
      int row = mf * 16 + ln;
      int uu = it * 4 + hi4;
      int phys = (uu & ~7) | ((uu & 7) ^ (row & 7));
      ah[mf] = *(const bf16x8*)&smAh[row * 512 + phys * 8];
      if constexpr (SPLIT) al[mf] = *(const bf16x8*)&smAl[row * 512 + phys * 8];
    }
#pragma unroll
    for (int mf = 0; mf < 2; ++mf)
#pragma unroll
      for (int nf = 0; nf < 4; ++nf) {
        acc[mf][nf] = mfma_bf16(ah[mf], bc[nf], acc[mf][nf]);
        if constexpr (SPLIT) acc[mf][nf] = mfma_bf16(al[mf], bc[nf], acc[mf][nf]);
      }
    if (it < 15) {
#pragma unroll
      for (int nf = 0; nf < 4; ++nf) bc[nf] = bn[nf];
    }
  }
#pragma unroll
  for (int mf = 0; mf < 2; ++mf)
#pragma unroll
    for (int nf = 0; nf < 4; ++nf)
#pragma unroll
      for (int e = 0; e < 4; ++e) {
        size_t off = (size_t)(m0 + mf * 16 + hi4 * 4 + e) * 512 +
                     w * 64 + nf * 16 + ln;
        float x = acc[mf][nf][e];
        bf16 h = (bf16)x;
        Ch[off] = h;
        if constexpr (SPLIT) Cl[off] = (bf16)(x - (float)h);
      }
}

// ================= single fused kernel: 256 blocks x 512 threads ===========
__global__ __launch_bounds__(512, 2) void fused_kernel(
    const float* __restrict__ q, const float* __restrict__ k,
    const float* __restrict__ v, const float* __restrict__ Wq,
    const float* __restrict__ Wk, const float* __restrict__ Wv,
    const float* __restrict__ Wo, bf16* __restrict__ WT,
    bf16* __restrict__ Qhi, bf16* __restrict__ Qlo,
    bf16* __restrict__ Khi, bf16* __restrict__ Klo,
    bf16* __restrict__ Vb, bf16* __restrict__ AO, float* __restrict__ out,
    unsigned* __restrict__ bar0, unsigned* __restrict__ bar1,
    unsigned* __restrict__ bar2) {
  __shared__ __align__(128) char smem[114688];   // 112 KB -> 1 block/CU
  const int bid = blockIdx.x;
  const int t = threadIdx.x;

  // ---------- phase 0: weight transpose+convert WT[mat][n][k] -------------
  {
    float* tile = (float*)smem;   // 64*65 floats
    const int mat = bid >> 6;
    const int tb  = bid & 63;
    const int r0 = (tb >> 3) * 64;  // k block
    const int c0 = (tb & 7) * 64;   // n block
    const float* W = (mat == 0) ? Wq : (mat == 1) ? Wk : (mat == 2) ? Wv : Wo;
#pragma unroll
    for (int i = 0; i < 8; ++i) {
      int idx = i * 512 + t;
      int r = idx >> 6, c = idx & 63;
      tile[r * 65 + c] = W[(size_t)(r0 + r) * DM + c0 + c];
    }
    __syncthreads();
#pragma unroll
    for (int i = 0; i < 8; ++i) {
      int idx = i * 512 + t;
      int r = idx >> 6, c = idx & 63;   // out row n=c0+r, col k=r0+c
      WT[(size_t)mat * DM * DM + (size_t)(c0 + r) * DM + r0 + c] =
          (bf16)tile[c * 65 + r];
    }
  }
  gbar(bar0);

  // ---------- phase 1: Q/K/V projection (A-stationary, barrier-free loop) --
  {
    bf16* smAh = (bf16*)smem;             // [32][512]
    bf16* smAl = (bf16*)(smem + 32768);
    const int pj = ((bid & 7) << 5) | (bid >> 3);  // XCD-chunked job id
    if (pj < 128) {
      proj_job<true>(q, WT, Qhi, Qlo, pj * 32, smAh, smAl);
    } else if (pj < 192) {
      proj_job<true>(k, WT + (size_t)DM * DM, Khi, Klo, (pj - 128) * 32,
                     smAh, smAl);
    } else {
      proj_job<false>(v, WT + (size_t)2 * DM * DM, Vb, nullptr, (pj - 192) * 32,
                      smAh, smAl);
    }
  }
  gbar(bar1);

  // ---------- phase 2: banded attention (r3 body verbatim) -----------------
  {
    bf16* smQh = (bf16*)smem;
    bf16* smQl = (bf16*)(smem + 16384);
    bf16* smKh = (bf16*)(smem + 32768);
    bf16* smKl = (bf16*)(smem + 49152);
    bf16* smVt = (bf16*)(smem + 65536);   // [64][128] swizzled
    bf16* smP  = (bf16*)(smem + 81920);   // [128][128] swizzled
    const int qt = bid & 15;
    const int h  = (bid >> 4) & 7;
    const int b  = bid >> 7;
    const int j0 = qt * 128;
    const int pbase = (j0 >> 1) - 63;
    const int lane = t & 63, w = t >> 6;
    const int ln = lane & 15, hi4 = lane >> 4;

#pragma unroll
    for (int i = 0; i < 2; ++i) {
      int idx = i * 512 + t;
      int r = idx >> 3, u = idx & 7;
      int sw = r * 64 + ((u ^ (r & 7)) * 8);
      size_t qoff = ((size_t)(b * LQn + j0 + r)) * 512 + h * 64 + u * 8;
      *(bf16x8*)&smQh[sw] = *(const bf16x8*)(Qhi + qoff);
      *(bf16x8*)&smQl[sw] = *(const bf16x8*)(Qlo + qoff);
      int p = pbase + r;
      p = p < 0 ? 0 : (p > LKVn - 1 ? LKVn - 1 : p);
      size_t koff = ((size_t)(b * LKVn + p)) * 512 + h * 64 + u * 8;
      *(bf16x8*)&smKh[sw] = *(const bf16x8*)(Khi + koff);
      *(bf16x8*)&smKl[sw] = *(const bf16x8*)(Klo + koff);
      bf16x8 vv = *(const bf16x8*)(Vb + koff);
#pragma unroll
      for (int e = 0; e < 8; ++e) {
        int rv = u * 8 + e;
        smVt[rv * 128 + (((r >> 3) ^ (rv & 15)) * 8) + (r & 7)] = vv[e];
      }
    }
    __syncthreads();

    const f32x4 zf = {0.f, 0.f, 0.f, 0.f};
    f32x4 s[8];
#pragma unroll
    for (int cf = 0; cf < 8; ++cf) s[cf] = zf;
#pragma unroll
    for (int kk = 0; kk < 64; kk += 32) {
      const int ub = kk >> 3;
      int addrq = (w * 16 + ln) * 64 + (((ub + hi4) ^ (ln & 7)) * 8);
      bf16x8 ah = *(const bf16x8*)&smQh[addrq];
      bf16x8 al = *(const bf16x8*)&smQl[addrq];
#pragma unroll
      for (int cf = 0; cf < 8; ++cf) {
        int addrk = (cf * 16 + ln) * 64 + (((ub + hi4) ^ (ln & 7)) * 8);
        bf16x8 bh = *(const bf16x8*)&smKh[addrk];
        bf16x8 bl = *(const bf16x8*)&smKl[addrk];
        s[cf] = mfma_bf16(ah, bh, s[cf]);
        s[cf] = mfma_bf16(ah, bl, s[cf]);
        s[cf] = mfma_bf16(al, bh, s[cf]);
      }
    }

#pragma unroll
    for (int r = 0; r < 4; ++r) {
      int rloc = w * 16 + hi4 * 4 + r;
      int wlo = rloc >> 1;
      int colmin = wlo > -pbase ? wlo : -pbase;
      int colmax = wlo + 63;
      float sv[8];
      float mx = -1e30f;
#pragma unroll
      for (int cf = 0; cf < 8; ++cf) {
        int col = cf * 16 + ln;
        float val = s[cf][r];
        bool ok = (col >= colmin) && (col <= colmax);
        sv[cf] = ok ? val : -1e30f;
        mx = fmaxf(mx, sv[cf]);
      }
#pragma unroll
      for (int msk = 1; msk < 16; msk <<= 1) mx = fmaxf(mx, __shfl_xor(mx, msk, 64));
      float sum = 0.f;
#pragma unroll
      for (int cf = 0; cf < 8; ++cf) {
        sv[cf] = __expf(sv[cf] - mx);
        sum += sv[cf];
      }
#pragma unroll
      for (int msk = 1; msk < 16; msk <<= 1) sum += __shfl_xor(sum, msk, 64);
      float rs = 1.0f / sum;
#pragma unroll
      for (int cf = 0; cf < 8; ++cf) {
        int uu = cf * 2 + (ln >> 3);
        smP[rloc * 128 + ((uu ^ (rloc & 15)) * 8) + (ln & 7)] = (bf16)(sv[cf] * rs);
      }
    }
    __syncthreads();

    f32x4 o[4];
#pragma unroll
    for (int nf = 0; nf < 4; ++nf) o[nf] = zf;
#pragma unroll
    for (int kk = 0; kk < 128; kk += 32) {
      const int ub = kk >> 3;
      bf16x8 pa = *(const bf16x8*)&smP[(w * 16 + ln) * 128 + (((ub + hi4) ^ ln) * 8)];
#pragma unroll
      for (int nf = 0; nf < 4; ++nf) {
        int d = nf * 16 + ln;
        bf16x8 vf = *(const bf16x8*)&smVt[d * 128 + (((ub + hi4) ^ ln) * 8)];
        o[nf] = mfma_bf16(pa, vf, o[nf]);
      }
    }

#pragma unroll
    for (int nf = 0; nf < 4; ++nf)
#pragma unroll
      for (int e = 0; e < 4; ++e) {
        int rloc = w * 16 + hi4 * 4 + e;
        AO[((size_t)(b * LQn + j0 + rloc)) * 512 + h * 64 + nf * 16 + ln] =
            (bf16)o[nf][e];
      }
  }
  gbar(bar2);

  // ---------- phase 3: output projection (64m x 128n, dbuf, 1 bar/step) ----
  {
    bf16* smA = (bf16*)smem;               // 2 x [64][64]
    bf16* smB = (bf16*)(smem + 16384);     // 2 x [128][64]
    const bf16* Bo = WT + (size_t)3 * DM * DM;
    const int oj = ((bid & 7) << 5) | (bid >> 3);  // XCD-chunked
    const int m0 = (oj >> 2) * 64, n0 = (oj & 3) * 128;
    const int lane = t & 63, w = t >> 6;
    const int ln = lane & 15, hi4 = lane >> 4;
    const int wr = w >> 2, wc = w & 3;
    const int rA = t >> 3, uA = t & 7;
    const f32x4 zf = {0.f, 0.f, 0.f, 0.f};
    f32x4 acc[2][2];
#pragma unroll
    for (int a = 0; a < 2; ++a)
#pragma unroll
      for (int b2 = 0; b2 < 2; ++b2) acc[a][b2] = zf;

    bf16x8 avr, bvr[2];
    auto LDo = [&](int ko) {
      avr = *(const bf16x8*)(AO + (size_t)(m0 + rA) * 512 + ko + uA * 8);
#pragma unroll
      for (int i = 0; i < 2; ++i) {
        int idx = i * 512 + t;
        int r = idx >> 3, u = idx & 7;
        bvr[i] = *(const bf16x8*)(Bo + (size_t)(n0 + r) * 512 + ko + u * 8);
      }
    };
    auto WRo = [&](int buf) {
      *(bf16x8*)&smA[buf * 4096 + rA * 64 + ((uA ^ (rA & 7)) * 8)] = avr;
#pragma unroll
      for (int i = 0; i < 2; ++i) {
        int idx = i * 512 + t;
        int r = idx >> 3, u = idx & 7;
        *(bf16x8*)&smB[buf * 8192 + r * 64 + ((u ^ (r & 7)) * 8)] = bvr[i];
      }
    };

    LDo(0);
    WRo(0);
    __syncthreads();
    int buf = 0;
    for (int kt = 0; kt < 8; ++kt) {
      if (kt < 7) LDo((kt + 1) * 64);
#pragma unroll
      for (int kk2 = 0; kk2 < 2; ++kk2) {
        const int ub = kk2 * 4;
        bf16x8 af[2], bh[2];
#pragma unroll
        for (int mf = 0; mf < 2; ++mf)
          af[mf] = *(const bf16x8*)&smA[buf * 4096 + (wr * 32 + mf * 16 + ln) * 64 +
                                        (((ub + hi4) ^ (ln & 7)) * 8)];
#pragma unroll
        for (int nf = 0; nf < 2; ++nf)
          bh[nf] = *(const bf16x8*)&smB[buf * 8192 + (wc * 32 + nf * 16 + ln) * 64 +
                                        (((ub + hi4) ^ (ln & 7)) * 8)];
#pragma unroll
        for (int mf = 0; mf < 2; ++mf)
#pragma unroll
          for (int nf = 0; nf < 2; ++nf)
            acc[mf][nf] = mfma_bf16(af[mf], bh[nf], acc[mf][nf]);
      }
      if (kt < 7) WRo(buf ^ 1);
      __syncthreads();
      buf ^= 1;
    }
#pragma unroll
    for (int mf = 0; mf < 2; ++mf)
#pragma unroll
      for (int nf = 0; nf < 2; ++nf)
#pragma unroll
        for (int e = 0; e < 4; ++e)
          out[(size_t)(m0 + wr * 32 + mf * 16 + hi4 * 4 + e) * 512 +
              n0 + wc * 32 + nf * 16 + ln] = acc[mf][nf][e];
  }
}

extern "C" void kernel_launch(void* const* d_in, const int* in_sizes, int n_in,
                              void* d_out, int out_size, void* d_ws, size_t ws_size,
                              hipStream_t stream) {
  const float* q    = (const float*)d_in[0];
  const float* k    = (const float*)d_in[1];
  const float* v    = (const float*)d_in[2];
  const float* Wq   = (const float*)d_in[3];
  const float* Wk   = (const float*)d_in[4];
  const float* Wv   = (const float*)d_in[5];
  const float* Wout = (const float*)d_in[6];
  float* out = (float*)d_out;

  char* ws = (char*)d_ws;
  bf16* WT   = (bf16*)ws;                          // 2 MB
  bf16* Qhi  = (bf16*)(ws + (size_t)(2  << 20));   // 4 MB
  bf16* Qlo  = (bf16*)(ws + (size_t)(6  << 20));   // 4 MB
  bf16* Khi  = (bf16*)(ws + (size_t)(10 << 20));   // 2 MB
  bf16* Klo  = (bf16*)(ws + (size_t)(12 << 20));   // 2 MB
  bf16* Vbuf = (bf16*)(ws + (size_t)(14 << 20));   // 2 MB
  bf16* AO   = (bf16*)(ws + (size_t)(16 << 20));   // 4 MB
  unsigned* bar0 = (unsigned*)(ws + (size_t)(20 << 20));
  unsigned* bar1 = bar0 + 256;
  unsigned* bar2 = bar0 + 512;

  hipMemsetAsync(bar0, 0, 3 * 256 * sizeof(unsigned), stream);
  fused_kernel<<<256, 512, 0, stream>>>(q, k, v, Wq, Wk, Wv, Wout, WT,
                                        Qhi, Qlo, Khi, Klo, Vbuf, AO, out,
                                        bar0, bar1, bar2);
}

// Round 10
// 41.900 us; speedup vs baseline: 2.3643x; 2.3643x over previous
//
#include <hip/hip_runtime.h>
#include <stdint.h>

typedef _Float16 f16;
typedef _Float16 f16x8 __attribute__((ext_vector_type(8)));
typedef float f32x4 __attribute__((ext_vector_type(4)));

#define LQn   2048
#define LKVn  1024
#define DM    512
#define NH    8

static __device__ __forceinline__ f32x4 mfma_f16(f16x8 a, f16x8 b, f32x4 c) {
  return __builtin_amdgcn_mfma_f32_16x16x32_f16(a, b, c, 0, 0, 0);
}

// ---------- weight transpose+convert: WT[mat][n*512+k] = (f16)W[k*512+n]
__global__ __launch_bounds__(256) void transpose_w_kernel(
    const float* __restrict__ Wq, const float* __restrict__ Wk,
    const float* __restrict__ Wv, const float* __restrict__ Wo,
    f16* __restrict__ WT) {
  __shared__ float tile[64 * 65];
  const int bid = blockIdx.x;
  const int mat = bid >> 6;
  const int tb  = bid & 63;
  const int r0 = (tb >> 3) * 64;  // k block
  const int c0 = (tb & 7) * 64;   // n block
  const float* W = (mat == 0) ? Wq : (mat == 1) ? Wk : (mat == 2) ? Wv : Wo;
  const int t = threadIdx.x;
#pragma unroll
  for (int i = 0; i < 16; ++i) {
    int idx = i * 256 + t;
    int r = idx >> 6, c = idx & 63;
    tile[r * 65 + c] = W[(size_t)(r0 + r) * DM + c0 + c];
  }
  __syncthreads();
#pragma unroll
  for (int i = 0; i < 16; ++i) {
    int idx = i * 256 + t;
    int r = idx >> 6, c = idx & 63;  // out row n=c0+r, col k=r0+c
    WT[(size_t)mat * DM * DM + (size_t)(c0 + r) * DM + r0 + c] =
        (f16)tile[c * 65 + r];
  }
}

// ---------- projection tile 128x128, 512 threads (8 waves, 2M x 4N).
// Single-precision-f16 path (no hi/lo split). Structure identical to the
// proven 46.0-us build, minus the split.
__device__ __forceinline__ void proj_tile(const float* __restrict__ Ap,
                                          const f16* __restrict__ Bp,
                                          f16* __restrict__ C,
                                          int m0, int n0,
                                          f16* smA, f16* smB) {
  const int t = threadIdx.x;
  const int lane = t & 63;
  const int w = t >> 6;            // 0..7
  const int ln = lane & 15, hi4 = lane >> 4;
  const int wr = w >> 2, wc = w & 3;
  const f32x4 zf = {0.f, 0.f, 0.f, 0.f};
  f32x4 acc[4][2];
#pragma unroll
  for (int a = 0; a < 4; ++a)
#pragma unroll
    for (int b = 0; b < 2; ++b) acc[a][b] = zf;

  for (int k0 = 0; k0 < 512; k0 += 64) {
    f16x8 av[2], bv[2];
#pragma unroll
    for (int i = 0; i < 2; ++i) {
      int idx = i * 512 + t;        // 1024 units of 8 elems
      int r = idx >> 3, u = idx & 7;
      const float* g = Ap + (size_t)(m0 + r) * 512 + k0 + u * 8;
      f32x4 x0 = *(const f32x4*)g, x1 = *(const f32x4*)(g + 4);
      f16x8 hv;
#pragma unroll
      for (int e = 0; e < 4; ++e) { hv[e] = (f16)x0[e]; hv[4 + e] = (f16)x1[e]; }
      av[i] = hv;
      bv[i] = *(const f16x8*)(Bp + (size_t)(n0 + r) * 512 + k0 + u * 8);
    }
    __syncthreads();
#pragma unroll
    for (int i = 0; i < 2; ++i) {
      int idx = i * 512 + t;
      int r = idx >> 3, u = idx & 7;
      int sw = r * 64 + ((u ^ (r & 7)) * 8);
      *(f16x8*)&smA[sw] = av[i];
      *(f16x8*)&smB[sw] = bv[i];
    }
    __syncthreads();
#pragma unroll
    for (int kk = 0; kk < 64; kk += 32) {
      const int ub = kk >> 3;
      f16x8 ah[4], bh[2];
#pragma unroll
      for (int mf = 0; mf < 4; ++mf) {
        int row = wr * 64 + mf * 16 + ln;
        ah[mf] = *(const f16x8*)&smA[row * 64 + (((ub + hi4) ^ (ln & 7)) * 8)];
      }
#pragma unroll
      for (int nf = 0; nf < 2; ++nf) {
        int row = wc * 32 + nf * 16 + ln;
        bh[nf] = *(const f16x8*)&smB[row * 64 + (((ub + hi4) ^ (ln & 7)) * 8)];
      }
#pragma unroll
      for (int mf = 0; mf < 4; ++mf)
#pragma unroll
        for (int nf = 0; nf < 2; ++nf)
          acc[mf][nf] = mfma_f16(ah[mf], bh[nf], acc[mf][nf]);
    }
  }
#pragma unroll
  for (int mf = 0; mf < 4; ++mf)
#pragma unroll
    for (int nf = 0; nf < 2; ++nf)
#pragma unroll
      for (int e = 0; e < 4; ++e) {
        size_t off = (size_t)(m0 + wr * 64 + mf * 16 + hi4 * 4 + e) * 512 +
                     n0 + wc * 32 + nf * 16 + ln;
        C[off] = (f16)acc[mf][nf][e];
      }
}

// ---------- fused Q/K/V projection
__global__ __launch_bounds__(512, 2) void proj_kernel(
    const float* __restrict__ q, const float* __restrict__ k,
    const float* __restrict__ v, const f16* __restrict__ WT,
    f16* __restrict__ Qf, f16* __restrict__ Kf, f16* __restrict__ Vf) {
  __shared__ f16 smA[128 * 64];
  __shared__ f16 smB[128 * 64];
  const int bid = blockIdx.x;
  if (bid < 128) {            // Q: 32x4 tiles
    int m0 = (bid >> 2) * 128, n0 = (bid & 3) * 128;
    proj_tile(q, WT, Qf, m0, n0, smA, smB);
  } else if (bid < 192) {     // K: 16x4 tiles
    int b2 = bid - 128;
    int m0 = (b2 >> 2) * 128, n0 = (b2 & 3) * 128;
    proj_tile(k, WT + (size_t)DM * DM, Kf, m0, n0, smA, smB);
  } else {                    // V: 16x4 tiles
    int b2 = bid - 192;
    int m0 = (b2 >> 2) * 128, n0 = (b2 & 3) * 128;
    proj_tile(v, WT + (size_t)2 * DM * DM, Vf, m0, n0, smA, smB);
  }
}

// ---------- output projection: 64x128 tiles, 256 blocks, 4 waves
__global__ __launch_bounds__(256) void outproj_kernel(
    const f16* __restrict__ AO, const f16* __restrict__ Bo,
    float* __restrict__ out) {
  __shared__ f16 smA[64 * 64];
  __shared__ f16 smB[128 * 64];
  const int bid = blockIdx.x;
  const int m0 = (bid >> 2) * 64, n0 = (bid & 3) * 128;
  const int t = threadIdx.x;
  const int lane = t & 63;
  const int w = t >> 6;            // 0..3
  const int ln = lane & 15, hi4 = lane >> 4;
  const f32x4 zf = {0.f, 0.f, 0.f, 0.f};
  f32x4 acc[4][2];
#pragma unroll
  for (int a = 0; a < 4; ++a)
#pragma unroll
    for (int b = 0; b < 2; ++b) acc[a][b] = zf;

  for (int k0 = 0; k0 < 512; k0 += 64) {
    f16x8 av[2], bv[4];
#pragma unroll
    for (int i = 0; i < 2; ++i) {
      int idx = i * 256 + t;        // 512 units of A
      int r = idx >> 3, u = idx & 7;
      av[i] = *(const f16x8*)(AO + (size_t)(m0 + r) * 512 + k0 + u * 8);
    }
#pragma unroll
    for (int i = 0; i < 4; ++i) {
      int idx = i * 256 + t;        // 1024 units of B
      int r = idx >> 3, u = idx & 7;
      bv[i] = *(const f16x8*)(Bo + (size_t)(n0 + r) * 512 + k0 + u * 8);
    }
    __syncthreads();
#pragma unroll
    for (int i = 0; i < 2; ++i) {
      int idx = i * 256 + t;
      int r = idx >> 3, u = idx & 7;
      *(f16x8*)&smA[r * 64 + ((u ^ (r & 7)) * 8)] = av[i];
    }
#pragma unroll
    for (int i = 0; i < 4; ++i) {
      int idx = i * 256 + t;
      int r = idx >> 3, u = idx & 7;
      *(f16x8*)&smB[r * 64 + ((u ^ (r & 7)) * 8)] = bv[i];
    }
    __syncthreads();
#pragma unroll
    for (int kk = 0; kk < 64; kk += 32) {
      const int ub = kk >> 3;
      f16x8 af[4], bh[2];
#pragma unroll
      for (int mf = 0; mf < 4; ++mf) {
        int row = mf * 16 + ln;
        af[mf] = *(const f16x8*)&smA[row * 64 + (((ub + hi4) ^ (ln & 7)) * 8)];
      }
#pragma unroll
      for (int nf = 0; nf < 2; ++nf) {
        int row = w * 32 + nf * 16 + ln;
        bh[nf] = *(const f16x8*)&smB[row * 64 + (((ub + hi4) ^ (ln & 7)) * 8)];
      }
#pragma unroll
      for (int mf = 0; mf < 4; ++mf)
#pragma unroll
        for (int nf = 0; nf < 2; ++nf)
          acc[mf][nf] = mfma_f16(af[mf], bh[nf], acc[mf][nf]);
    }
  }
#pragma unroll
  for (int mf = 0; mf < 4; ++mf)
#pragma unroll
    for (int nf = 0; nf < 2; ++nf)
#pragma unroll
      for (int e = 0; e < 4; ++e)
        out[(size_t)(m0 + mf * 16 + hi4 * 4 + e) * 512 +
            n0 + w * 32 + nf * 16 + ln] = acc[mf][nf][e];
}

// ---------- banded attention: one (b,h,128-query tile) per block, 512 thr
__global__ __launch_bounds__(512, 2) void attn_kernel(
    const f16* __restrict__ Qf, const f16* __restrict__ Kf,
    const f16* __restrict__ Vf, f16* __restrict__ AO) {
  __shared__ f16 smQ[128 * 64];
  __shared__ f16 smK[128 * 64];
  __shared__ f16 smVt[64 * 128];   // [d][p], swizzled
  __shared__ f16 smP[128 * 128];   // swizzled
  const int bid = blockIdx.x;
  const int qt = bid & 15;
  const int h  = (bid >> 4) & 7;
  const int b  = bid >> 7;
  const int j0 = qt * 128;
  const int pbase = (j0 >> 1) - 63;  // KV rows pbase..pbase+127
  const int t = threadIdx.x;
  const int lane = t & 63, w = t >> 6;   // 8 waves, 16 q-rows each
  const int ln = lane & 15, hi4 = lane >> 4;

  // stage Q,K (swizzled [128][64]) and V transposed (swizzled [64][128])
#pragma unroll
  for (int i = 0; i < 2; ++i) {
    int idx = i * 512 + t;          // 1024 units
    int r = idx >> 3, u = idx & 7;
    int sw = r * 64 + ((u ^ (r & 7)) * 8);
    size_t qoff = ((size_t)(b * LQn + j0 + r)) * 512 + h * 64 + u * 8;
    *(f16x8*)&smQ[sw] = *(const f16x8*)(Qf + qoff);
    int p = pbase + r;
    p = p < 0 ? 0 : (p > LKVn - 1 ? LKVn - 1 : p);  // clamped rows masked later
    size_t koff = ((size_t)(b * LKVn + p)) * 512 + h * 64 + u * 8;
    *(f16x8*)&smK[sw] = *(const f16x8*)(Kf + koff);
    f16x8 vv = *(const f16x8*)(Vf + koff);
#pragma unroll
    for (int e = 0; e < 8; ++e) {
      int rv = u * 8 + e;           // d-row of smVt
      smVt[rv * 128 + (((r >> 3) ^ (rv & 15)) * 8) + (r & 7)] = vv[e];
    }
  }
  __syncthreads();

  // S = Q K^T  (this wave: q-rows w*16..w*16+15, all 128 kv cols)
  const f32x4 zf = {0.f, 0.f, 0.f, 0.f};
  f32x4 s[8];
#pragma unroll
  for (int cf = 0; cf < 8; ++cf) s[cf] = zf;
#pragma unroll
  for (int kk = 0; kk < 64; kk += 32) {
    const int ub = kk >> 3;
    int addrq = (w * 16 + ln) * 64 + (((ub + hi4) ^ (ln & 7)) * 8);
    f16x8 ah = *(const f16x8*)&smQ[addrq];
#pragma unroll
    for (int cf = 0; cf < 8; ++cf) {
      int addrk = (cf * 16 + ln) * 64 + (((ub + hi4) ^ (ln & 7)) * 8);
      f16x8 bh = *(const f16x8*)&smK[addrk];
      s[cf] = mfma_f16(ah, bh, s[cf]);
    }
  }

  // mask (band + left clamp), wave-parallel softmax, P -> f16 LDS (swizzled)
#pragma unroll
  for (int r = 0; r < 4; ++r) {
    int rloc = w * 16 + hi4 * 4 + r;
    int wlo = rloc >> 1;
    int colmin = wlo > -pbase ? wlo : -pbase;
    int colmax = wlo + 63;
    float sv[8];
    float mx = -1e30f;
#pragma unroll
    for (int cf = 0; cf < 8; ++cf) {
      int col = cf * 16 + ln;
      float val = s[cf][r];
      bool ok = (col >= colmin) && (col <= colmax);
      sv[cf] = ok ? val : -1e30f;
      mx = fmaxf(mx, sv[cf]);
    }
#pragma unroll
    for (int msk = 1; msk < 16; msk <<= 1) mx = fmaxf(mx, __shfl_xor(mx, msk, 64));
    float sum = 0.f;
#pragma unroll
    for (int cf = 0; cf < 8; ++cf) {
      sv[cf] = __expf(sv[cf] - mx);
      sum += sv[cf];
    }
#pragma unroll
    for (int msk = 1; msk < 16; msk <<= 1) sum += __shfl_xor(sum, msk, 64);
    float rs = 1.0f / sum;
#pragma unroll
    for (int cf = 0; cf < 8; ++cf) {
      int uu = cf * 2 + (ln >> 3);
      smP[rloc * 128 + ((uu ^ (rloc & 15)) * 8) + (ln & 7)] = (f16)(sv[cf] * rs);
    }
  }
  __syncthreads();

  // O = P @ V   (wave's 16 q-rows x 64 d)
  f32x4 o[4];
#pragma unroll
  for (int nf = 0; nf < 4; ++nf) o[nf] = zf;
#pragma unroll
  for (int kk = 0; kk < 128; kk += 32) {
    const int ub = kk >> 3;
    f16x8 pa = *(const f16x8*)&smP[(w * 16 + ln) * 128 + (((ub + hi4) ^ ln) * 8)];
#pragma unroll
    for (int nf = 0; nf < 4; ++nf) {
      int d = nf * 16 + ln;
      f16x8 vf = *(const f16x8*)&smVt[d * 128 + (((ub + hi4) ^ ln) * 8)];
      o[nf] = mfma_f16(pa, vf, o[nf]);
    }
  }

  // write AO[b, j0+rloc, h*64 + d]
#pragma unroll
  for (int nf = 0; nf < 4; ++nf)
#pragma unroll
    for (int e = 0; e < 4; ++e) {
      int rloc = w * 16 + hi4 * 4 + e;
      AO[((size_t)(b * LQn + j0 + rloc)) * 512 + h * 64 + nf * 16 + ln] =
          (f16)o[nf][e];
    }
}

extern "C" void kernel_launch(void* const* d_in, const int* in_sizes, int n_in,
                              void* d_out, int out_size, void* d_ws, size_t ws_size,
                              hipStream_t stream) {
  const float* q    = (const float*)d_in[0];
  const float* k    = (const float*)d_in[1];
  const float* v    = (const float*)d_in[2];
  const float* Wq   = (const float*)d_in[3];
  const float* Wk   = (const float*)d_in[4];
  const float* Wv   = (const float*)d_in[5];
  const float* Wout = (const float*)d_in[6];
  float* out = (float*)d_out;

  char* ws = (char*)d_ws;
  f16* WT  = (f16*)ws;                          // 4*512*512*2 = 2 MB
  f16* Qf  = (f16*)(ws + (size_t)(2 << 20));    // 2048*2*512*2 = 2 MB... (4096 rows) = 4 MB
  f16* Kf  = (f16*)(ws + (size_t)(6 << 20));    // 2048*512*2 = 2 MB
  f16* Vf  = (f16*)(ws + (size_t)(8 << 20));    // 2 MB
  f16* AO  = (f16*)(ws + (size_t)(10 << 20));   // 4 MB  (total 14 MB)

  transpose_w_kernel<<<256, 256, 0, stream>>>(Wq, Wk, Wv, Wout, WT);
  proj_kernel<<<256, 512, 0, stream>>>(q, k, v, WT, Qf, Kf, Vf);
  attn_kernel<<<256, 512, 0, stream>>>(Qf, Kf, Vf, AO);
  outproj_kernel<<<256, 256, 0, stream>>>(AO, WT + (size_t)3 * DM * DM, out);
}

// Round 11
// 39.438 us; speedup vs baseline: 2.5119x; 1.0624x over previous
//
#include <hip/hip_runtime.h>
#include <stdint.h>

typedef _Float16 f16;
typedef _Float16 f16x8 __attribute__((ext_vector_type(8)));
typedef float f32x4 __attribute__((ext_vector_type(4)));

#define LQn   2048
#define LKVn  1024
#define DM    512
#define NH    8
#define WSZ   262144   // f16 elems per packed weight matrix (512 KB)

static __device__ __forceinline__ f32x4 mfma_f16(f16x8 a, f16x8 b, f32x4 c) {
  return __builtin_amdgcn_mfma_f32_16x16x32_f16(a, b, c, 0, 0, 0);
}

// ---------- weight transpose + convert + FRAGMENT-PACK.
// WTf[mat] layout: elem addr = ((n16*16 + it)*64 + lane)*8 + e  where
// n = n16*16 + ln, k = it*32 + hi4*8 + e, lane = hi4*16 + ln.
// A wave's B-fragment load (64 lanes x 16B) is then 1KB CONTIGUOUS.
__global__ __launch_bounds__(256) void transpose_w_kernel(
    const float* __restrict__ Wq, const float* __restrict__ Wk,
    const float* __restrict__ Wv, const float* __restrict__ Wo,
    f16* __restrict__ WTf) {
  __shared__ float tile[64 * 65];
  const int bid = blockIdx.x;
  const int mat = bid >> 6;
  const int tb  = bid & 63;
  const int r0 = (tb >> 3) * 64;  // k block
  const int c0 = (tb & 7) * 64;   // n block
  const float* W = (mat == 0) ? Wq : (mat == 1) ? Wk : (mat == 2) ? Wv : Wo;
  const int t = threadIdx.x;
#pragma unroll
  for (int i = 0; i < 16; ++i) {
    int idx = i * 256 + t;
    int r = idx >> 6, c = idx & 63;
    tile[r * 65 + c] = W[(size_t)(r0 + r) * DM + c0 + c];
  }
  __syncthreads();
#pragma unroll
  for (int i = 0; i < 16; ++i) {
    int idx = i * 256 + t;
    int r = idx >> 6, c = idx & 63;
    int n = c0 + r, kk = r0 + c;       // logical WT[n][k] = W[k][n]
    int n16 = n >> 4, ln = n & 15;
    int it = kk >> 5, h4 = (kk >> 3) & 3, e = kk & 7;
    int lane = h4 * 16 + ln;
    WTf[(size_t)mat * WSZ + ((size_t)(n16 * 16 + it) * 64 + lane) * 8 + e] =
        (f16)tile[c * 65 + r];
  }
}

// ---------- A-stationary projection: 256 blocks x 512 thr.
// Block = 32-row A-slab (staged once to LDS) x all 512 n-cols.
// Wave w owns n in [w*64, w*64+64). B streamed from fragment-packed WTf
// (L2-hot, fully coalesced), 2-deep register prefetch. NO barriers in k-loop.
__global__ __launch_bounds__(512) void proj_kernel(
    const float* __restrict__ q, const float* __restrict__ k,
    const float* __restrict__ v, const f16* __restrict__ WTf,
    f16* __restrict__ Qf, f16* __restrict__ Kf, f16* __restrict__ Vf) {
  __shared__ f16 smA[32 * 512];   // 32 KB
  const int bid = blockIdx.x;
  const float* A;
  const f16* Bf;
  f16* C;
  int m0;
  if (bid < 128)      { A = q; Bf = WTf;            C = Qf; m0 = bid * 32; }
  else if (bid < 192) { A = k; Bf = WTf + WSZ;      C = Kf; m0 = (bid - 128) * 32; }
  else                { A = v; Bf = WTf + 2 * WSZ;  C = Vf; m0 = (bid - 192) * 32; }

  const int t = threadIdx.x;
  const int lane = t & 63;
  const int w = t >> 6;            // 0..7
  const int ln = lane & 15, hi4 = lane >> 4;

  // stage A-slab [32][512] fp32 -> f16, unit-swizzled; coalesced 32B/lane
#pragma unroll
  for (int i = 0; i < 4; ++i) {
    int idx = i * 512 + t;
    int r = idx >> 6, u = idx & 63;
    const float* g = A + (size_t)(m0 + r) * 512 + u * 8;
    f32x4 x0 = *(const f32x4*)g, x1 = *(const f32x4*)(g + 4);
    f16x8 hv;
#pragma unroll
    for (int e = 0; e < 4; ++e) { hv[e] = (f16)x0[e]; hv[4 + e] = (f16)x1[e]; }
    int phys = (u & ~7) | ((u & 7) ^ (r & 7));
    *(f16x8*)&smA[r * 512 + phys * 8] = hv;
  }
  __syncthreads();

  const f16* gB = Bf + ((size_t)(w * 4) * 16 * 64 + lane) * 8;
  const f32x4 zf = {0.f, 0.f, 0.f, 0.f};
  f32x4 acc[2][4];
#pragma unroll
  for (int a = 0; a < 2; ++a)
#pragma unroll
    for (int b = 0; b < 4; ++b) acc[a][b] = zf;

  f16x8 buf0[4], buf1[4];
#pragma unroll
  for (int nf = 0; nf < 4; ++nf) buf0[nf] = *(const f16x8*)(gB + nf * 8192);
#pragma unroll
  for (int nf = 0; nf < 4; ++nf) buf1[nf] = *(const f16x8*)(gB + nf * 8192 + 512);

#pragma unroll
  for (int it = 0; it < 16; ++it) {
    f16x8 bfr[4], ah[2];
#pragma unroll
    for (int nf = 0; nf < 4; ++nf) bfr[nf] = (it & 1) ? buf1[nf] : buf0[nf];
    if (it + 2 < 16) {
#pragma unroll
      for (int nf = 0; nf < 4; ++nf) {
        f16x8 nv = *(const f16x8*)(gB + nf * 8192 + (it + 2) * 512);
        if (it & 1) buf1[nf] = nv; else buf0[nf] = nv;
      }
    }
#pragma unroll
    for (int mf = 0; mf < 2; ++mf) {
      int row = mf * 16 + ln;
      int uu = it * 4 + hi4;
      int phys = (uu & ~7) | ((uu & 7) ^ (row & 7));
      ah[mf] = *(const f16x8*)&smA[row * 512 + phys * 8];
    }
#pragma unroll
    for (int mf = 0; mf < 2; ++mf)
#pragma unroll
      for (int nf = 0; nf < 4; ++nf)
        acc[mf][nf] = mfma_f16(ah[mf], bfr[nf], acc[mf][nf]);
  }

#pragma unroll
  for (int mf = 0; mf < 2; ++mf)
#pragma unroll
    for (int nf = 0; nf < 4; ++nf)
#pragma unroll
      for (int e = 0; e < 4; ++e) {
        size_t off = (size_t)(m0 + mf * 16 + hi4 * 4 + e) * 512 +
                     w * 64 + nf * 16 + ln;
        C[off] = (f16)acc[mf][nf][e];
      }
}

// ---------- A-stationary output projection: 256 blocks x 512 thr.
// Block = 16-row AO slab x all 512 n; barrier-free k-loop, packed Wo frags.
__global__ __launch_bounds__(512) void outproj_kernel(
    const f16* __restrict__ AO, const f16* __restrict__ WTf,
    float* __restrict__ out) {
  __shared__ f16 smA[16 * 512];   // 16 KB
  const int bid = blockIdx.x;
  const int m0 = bid * 16;
  const f16* Bf = WTf + (size_t)3 * WSZ;
  const int t = threadIdx.x;
  const int lane = t & 63;
  const int w = t >> 6;
  const int ln = lane & 15, hi4 = lane >> 4;

#pragma unroll
  for (int i = 0; i < 2; ++i) {
    int idx = i * 512 + t;
    int r = idx >> 6, u = idx & 63;
    f16x8 hv = *(const f16x8*)(AO + (size_t)(m0 + r) * 512 + u * 8);
    int phys = (u & ~7) | ((u & 7) ^ (r & 7));
    *(f16x8*)&smA[r * 512 + phys * 8] = hv;
  }
  __syncthreads();

  const f16* gB = Bf + ((size_t)(w * 4) * 16 * 64 + lane) * 8;
  const f32x4 zf = {0.f, 0.f, 0.f, 0.f};
  f32x4 acc[4];
#pragma unroll
  for (int b = 0; b < 4; ++b) acc[b] = zf;

  f16x8 buf0[4], buf1[4];
#pragma unroll
  for (int nf = 0; nf < 4; ++nf) buf0[nf] = *(const f16x8*)(gB + nf * 8192);
#pragma unroll
  for (int nf = 0; nf < 4; ++nf) buf1[nf] = *(const f16x8*)(gB + nf * 8192 + 512);

#pragma unroll
  for (int it = 0; it < 16; ++it) {
    f16x8 bfr[4], av;
#pragma unroll
    for (int nf = 0; nf < 4; ++nf) bfr[nf] = (it & 1) ? buf1[nf] : buf0[nf];
    if (it + 2 < 16) {
#pragma unroll
      for (int nf = 0; nf < 4; ++nf) {
        f16x8 nv = *(const f16x8*)(gB + nf * 8192 + (it + 2) * 512);
        if (it & 1) buf1[nf] = nv; else buf0[nf] = nv;
      }
    }
    {
      int uu = it * 4 + hi4;
      int phys = (uu & ~7) | ((uu & 7) ^ (ln & 7));
      av = *(const f16x8*)&smA[ln * 512 + phys * 8];
    }
#pragma unroll
    for (int nf = 0; nf < 4; ++nf)
      acc[nf] = mfma_f16(av, bfr[nf], acc[nf]);
  }

#pragma unroll
  for (int nf = 0; nf < 4; ++nf)
#pragma unroll
    for (int e = 0; e < 4; ++e)
      out[(size_t)(m0 + hi4 * 4 + e) * 512 + w * 64 + nf * 16 + ln] = acc[nf][e];
}

// ---------- banded attention: verbatim from the 41.9-us r10 build.
__global__ __launch_bounds__(512, 2) void attn_kernel(
    const f16* __restrict__ Qf, const f16* __restrict__ Kf,
    const f16* __restrict__ Vf, f16* __restrict__ AO) {
  __shared__ f16 smQ[128 * 64];
  __shared__ f16 smK[128 * 64];
  __shared__ f16 smVt[64 * 128];   // [d][p], swizzled
  __shared__ f16 smP[128 * 128];   // swizzled
  const int bid = blockIdx.x;
  const int qt = bid & 15;
  const int h  = (bid >> 4) & 7;
  const int b  = bid >> 7;
  const int j0 = qt * 128;
  const int pbase = (j0 >> 1) - 63;  // KV rows pbase..pbase+127
  const int t = threadIdx.x;
  const int lane = t & 63, w = t >> 6;   // 8 waves, 16 q-rows each
  const int ln = lane & 15, hi4 = lane >> 4;

#pragma unroll
  for (int i = 0; i < 2; ++i) {
    int idx = i * 512 + t;          // 1024 units
    int r = idx >> 3, u = idx & 7;
    int sw = r * 64 + ((u ^ (r & 7)) * 8);
    size_t qoff = ((size_t)(b * LQn + j0 + r)) * 512 + h * 64 + u * 8;
    *(f16x8*)&smQ[sw] = *(const f16x8*)(Qf + qoff);
    int p = pbase + r;
    p = p < 0 ? 0 : (p > LKVn - 1 ? LKVn - 1 : p);  // clamped rows masked later
    size_t koff = ((size_t)(b * LKVn + p)) * 512 + h * 64 + u * 8;
    *(f16x8*)&smK[sw] = *(const f16x8*)(Kf + koff);
    f16x8 vv = *(const f16x8*)(Vf + koff);
#pragma unroll
    for (int e = 0; e < 8; ++e) {
      int rv = u * 8 + e;           // d-row of smVt
      smVt[rv * 128 + (((r >> 3) ^ (rv & 15)) * 8) + (r & 7)] = vv[e];
    }
  }
  __syncthreads();

  const f32x4 zf = {0.f, 0.f, 0.f, 0.f};
  f32x4 s[8];
#pragma unroll
  for (int cf = 0; cf < 8; ++cf) s[cf] = zf;
#pragma unroll
  for (int kk = 0; kk < 64; kk += 32) {
    const int ub = kk >> 3;
    int addrq = (w * 16 + ln) * 64 + (((ub + hi4) ^ (ln & 7)) * 8);
    f16x8 ah = *(const f16x8*)&smQ[addrq];
#pragma unroll
    for (int cf = 0; cf < 8; ++cf) {
      int addrk = (cf * 16 + ln) * 64 + (((ub + hi4) ^ (ln & 7)) * 8);
      f16x8 bh = *(const f16x8*)&smK[addrk];
      s[cf] = mfma_f16(ah, bh, s[cf]);
    }
  }

#pragma unroll
  for (int r = 0; r < 4; ++r) {
    int rloc = w * 16 + hi4 * 4 + r;
    int wlo = rloc >> 1;
    int colmin = wlo > -pbase ? wlo : -pbase;
    int colmax = wlo + 63;
    float sv[8];
    float mx = -1e30f;
#pragma unroll
    for (int cf = 0; cf < 8; ++cf) {
      int col = cf * 16 + ln;
      float val = s[cf][r];
      bool ok = (col >= colmin) && (col <= colmax);
      sv[cf] = ok ? val : -1e30f;
      mx = fmaxf(mx, sv[cf]);
    }
#pragma unroll
    for (int msk = 1; msk < 16; msk <<= 1) mx = fmaxf(mx, __shfl_xor(mx, msk, 64));
    float sum = 0.f;
#pragma unroll
    for (int cf = 0; cf < 8; ++cf) {
      sv[cf] = __expf(sv[cf] - mx);
      sum += sv[cf];
    }
#pragma unroll
    for (int msk = 1; msk < 16; msk <<= 1) sum += __shfl_xor(sum, msk, 64);
    float rs = 1.0f / sum;
#pragma unroll
    for (int cf = 0; cf < 8; ++cf) {
      int uu = cf * 2 + (ln >> 3);
      smP[rloc * 128 + ((uu ^ (rloc & 15)) * 8) + (ln & 7)] = (f16)(sv[cf] * rs);
    }
  }
  __syncthreads();

  f32x4 o[4];
#pragma unroll
  for (int nf = 0; nf < 4; ++nf) o[nf] = zf;
#pragma unroll
  for (int kk = 0; kk < 128; kk += 32) {
    const int ub = kk >> 3;
    f16x8 pa = *(const f16x8*)&smP[(w * 16 + ln) * 128 + (((ub + hi4) ^ ln) * 8)];
#pragma unroll
    for (int nf = 0; nf < 4; ++nf) {
      int d = nf * 16 + ln;
      f16x8 vf = *(const f16x8*)&smVt[d * 128 + (((ub + hi4) ^ ln) * 8)];
      o[nf] = mfma_f16(pa, vf, o[nf]);
    }
  }

#pragma unroll
  for (int nf = 0; nf < 4; ++nf)
#pragma unroll
    for (int e = 0; e < 4; ++e) {
      int rloc = w * 16 + hi4 * 4 + e;
      AO[((size_t)(b * LQn + j0 + rloc)) * 512 + h * 64 + nf * 16 + ln] =
          (f16)o[nf][e];
    }
}

extern "C" void kernel_launch(void* const* d_in, const int* in_sizes, int n_in,
                              void* d_out, int out_size, void* d_ws, size_t ws_size,
                              hipStream_t stream) {
  const float* q    = (const float*)d_in[0];
  const float* k    = (const float*)d_in[1];
  const float* v    = (const float*)d_in[2];
  const float* Wq   = (const float*)d_in[3];
  const float* Wk   = (const float*)d_in[4];
  const float* Wv   = (const float*)d_in[5];
  const float* Wout = (const float*)d_in[6];
  float* out = (float*)d_out;

  char* ws = (char*)d_ws;
  f16* WTf = (f16*)ws;                          // 4 * 512 KB = 2 MB (packed)
  f16* Qf  = (f16*)(ws + (size_t)(2 << 20));    // 4 MB
  f16* Kf  = (f16*)(ws + (size_t)(6 << 20));    // 2 MB
  f16* Vf  = (f16*)(ws + (size_t)(8 << 20));    // 2 MB
  f16* AO  = (f16*)(ws + (size_t)(10 << 20));   // 4 MB  (total 14 MB)

  transpose_w_kernel<<<256, 256, 0, stream>>>(Wq, Wk, Wv, Wout, WTf);
  proj_kernel<<<256, 512, 0, stream>>>(q, k, v, WTf, Qf, Kf, Vf);
  attn_kernel<<<256, 512, 0, stream>>>(Qf, Kf, Vf, AO);
  outproj_kernel<<<256, 512, 0, stream>>>(AO, WTf, out);
}